// Round 3
// baseline (549.758 us; speedup 1.0000x reference)
//
#include <hip/hip_runtime.h>
#include <math.h>

#define DIMM 128
#define NHEAD 8

typedef __attribute__((ext_vector_type(8))) short bf16x8;
typedef __attribute__((ext_vector_type(4))) float f32x4;

__device__ __forceinline__ unsigned short f2bf(float x) {
    union { float f; unsigned int u; } v; v.f = x;
    unsigned int r = v.u + 0x7FFFu + ((v.u >> 16) & 1u);
    return (unsigned short)(r >> 16);
}
__device__ __forceinline__ float bf2f(unsigned short u) {
    union { unsigned int u; float f; } v; v.u = ((unsigned int)u) << 16;
    return v.f;
}
__device__ __forceinline__ float gelu_exact(float x) {
    return 0.5f * x * (1.0f + erff(x * 0.70710678118654752f));
}

// ---------------------------------------------------------------------------
// Kernel 1: h1 = h @ W_in + b_in  (f32 compute), write comb cols 0..127 (bf16)
// plus attn_u = h1@Wu+bu, attn_v = h1@Wv (f32)
// ---------------------------------------------------------------------------
__global__ __launch_bounds__(256) void k_h1(
        const float* __restrict__ h,
        const float* __restrict__ W_in, const float* __restrict__ b_in,
        const float* __restrict__ Wu, const float* __restrict__ bu,
        const float* __restrict__ Wv,
        unsigned short* __restrict__ comb,   // [N][256] bf16
        float* __restrict__ attn_u, float* __restrict__ attn_v,
        int N)
{
    __shared__ float h_lds[16][128];
    __shared__ float h1_lds[16][130];
    int t = threadIdx.x;
    int row0 = blockIdx.x * 16;

    #pragma unroll
    for (int u = 0; u < 2; ++u) {
        int idx = t + u * 256;
        int r = idx >> 5;
        int c4 = idx & 31;
        float4 v = make_float4(0.f, 0.f, 0.f, 0.f);
        if (row0 + r < N) v = *(const float4*)(h + (size_t)(row0 + r) * DIMM + c4 * 4);
        *(float4*)&h_lds[r][c4 * 4] = v;
    }
    __syncthreads();

    int col = t & 127;
    int rgrp = t >> 7;
    float acc[8];
    float bi = b_in[col];
    #pragma unroll
    for (int i = 0; i < 8; ++i) acc[i] = bi;
    for (int k = 0; k < 128; ++k) {
        float w = W_in[k * DIMM + col];
        #pragma unroll
        for (int i = 0; i < 8; ++i) acc[i] += h_lds[rgrp * 8 + i][k] * w;
    }
    #pragma unroll
    for (int i = 0; i < 8; ++i) {
        int r = rgrp * 8 + i;
        h1_lds[r][col] = acc[i];
        if (row0 + r < N) comb[(size_t)(row0 + r) * 256 + col] = f2bf(acc[i]);
    }
    __syncthreads();

    {
        int r = t >> 4;
        int j = t & 15;
        int head = j & 7;
        bool isv = (j >= 8);
        const float* W = isv ? Wv : Wu;
        float a = isv ? 0.f : bu[head];
        for (int k = 0; k < 128; ++k) a += h1_lds[r][k] * W[k * NHEAD + head];
        if (row0 + r < N) {
            if (isv) attn_v[(size_t)(row0 + r) * NHEAD + head] = a;
            else     attn_u[(size_t)(row0 + r) * NHEAD + head] = a;
        }
    }
}

// ---------------------------------------------------------------------------
// Weight prep: W1 [256][512] f32 -> W1T [512][256] bf16 ; W2 [512][128] f32 ->
// W2T [128][512] bf16 (B^T panels for MFMA B-fragments)
// ---------------------------------------------------------------------------
__global__ __launch_bounds__(256) void k_prep(
        const float* __restrict__ W1, const float* __restrict__ W2,
        unsigned short* __restrict__ W1T, unsigned short* __restrict__ W2T)
{
    int i = blockIdx.x * 256 + threadIdx.x;
    if (i < 256 * 512) {
        int k = i >> 9, j = i & 511;
        W1T[(size_t)j * 256 + k] = f2bf(W1[i]);
    }
    if (i < 512 * 128) {
        int k = i >> 7, j = i & 127;
        W2T[(size_t)j * 512 + k] = f2bf(W2[i]);
    }
}

// ---------------------------------------------------------------------------
// CSR build: histogram -> scan -> two-level bucket sort
// bucket = dst >> 4  (16 nodes / bucket, ~512 edges, 2 KB output region)
// ---------------------------------------------------------------------------
__global__ void k_hist(const int* __restrict__ dst, int* __restrict__ counts, int E) {
    int e = blockIdx.x * blockDim.x + threadIdx.x;
    if (e < E) atomicAdd(&counts[dst[e]], 1);
}

__global__ __launch_bounds__(1024) void k_scan(
        const int* __restrict__ counts,
        int* __restrict__ row_ptr, int* __restrict__ bucket_cursor, int N, int E)
{
    __shared__ int wsum[16];
    int t = threadIdx.x;
    int chunk = (N + 1023) / 1024;
    int s = t * chunk;
    int epos = min(s + chunk, N);
    int local = 0;
    for (int i = s; i < epos; ++i) local += counts[i];

    int lane = t & 63, w = t >> 6;
    int incl = local;
    #pragma unroll
    for (int d = 1; d < 64; d <<= 1) {
        int v = __shfl_up(incl, d, 64);
        if (lane >= d) incl += v;
    }
    if (lane == 63) wsum[w] = incl;
    __syncthreads();
    if (t == 0) {
        int run = 0;
        #pragma unroll
        for (int i = 0; i < 16; ++i) { int v = wsum[i]; wsum[i] = run; run += v; }
    }
    __syncthreads();
    int run = wsum[w] + incl - local;
    for (int i = s; i < epos; ++i) {
        row_ptr[i] = run;
        if ((i & 15) == 0) bucket_cursor[i >> 4] = run;  // bucket base (chunk=N/1024 is mult of 16 here, but safe anyway via per-i check)
        run += counts[i];
    }
    if (t == 1023) row_ptr[N] = E;
}

// scatter edges into bucket regions (dense write heads -> L2 write combining)
__global__ void k_bucket(const int* __restrict__ src, const int* __restrict__ dst,
                         int* __restrict__ bucket_cursor,
                         unsigned long long* __restrict__ tmp, int E) {
    int e = blockIdx.x * blockDim.x + threadIdx.x;
    if (e < E) {
        int d = dst[e];
        int p = atomicAdd(&bucket_cursor[d >> 4], 1);
        tmp[p] = ((unsigned long long)(unsigned)d << 32) | (unsigned)src[e];
    }
}

// place edges at exact CSR positions (writes stay within 2 KB bucket region)
__global__ __launch_bounds__(256) void k_place(
        const unsigned long long* __restrict__ tmp,
        const int* __restrict__ row_ptr,
        int* __restrict__ src_sorted, int N) {
    __shared__ int curs[16];
    int b = blockIdx.x;
    int t = threadIdx.x;
    int n0 = b * 16;
    if (t < 16) curs[t] = row_ptr[min(n0 + t, N)];
    __syncthreads();
    int base = row_ptr[min(n0, N)];
    int end  = row_ptr[min(n0 + 16, N)];
    for (int e = base + t; e < end; e += 256) {
        unsigned long long u = tmp[e];
        int s = (int)(u & 0xffffffffULL);
        int d = (int)(u >> 32);
        int p = atomicAdd(&curs[d & 15], 1);
        src_sorted[p] = s;
    }
}

// ---------------------------------------------------------------------------
// per-dst-node online softmax + message aggregation (f32 math, bf16 h1 gather)
// ---------------------------------------------------------------------------
__device__ __forceinline__ float select8(const float v[8], int h) {
    float a = (h & 1) ? v[1] : v[0];
    float b = (h & 1) ? v[3] : v[2];
    float c = (h & 1) ? v[5] : v[4];
    float d = (h & 1) ? v[7] : v[6];
    float e = (h & 2) ? b : a;
    float f = (h & 2) ? d : c;
    return (h & 4) ? f : e;
}

__global__ __launch_bounds__(256) void k_agg(
        const unsigned short* __restrict__ comb_h1,   // [N][256] bf16, h1 = cols 0..127
        const float* __restrict__ attn_u, const float* __restrict__ attn_v,
        const int* __restrict__ row_ptr, const int* __restrict__ src_sorted,
        unsigned short* __restrict__ comb,            // msg -> cols 128..255
        int N)
{
    __shared__ float p_lds[4][64][8];
    __shared__ int   s_lds[4][64];
    int t = threadIdx.x;
    int w = t >> 6, lane = t & 63;
    int n = blockIdx.x * 4 + w;
    if (n >= N) return;
    int rs = row_ptr[n], re = row_ptr[n + 1];
    int deg = re - rs;
    unsigned short* msg_out = comb + (size_t)n * 256 + 128;
    if (deg == 0) {
        msg_out[lane] = 0;
        msg_out[64 + lane] = 0;
        return;
    }

    float av[8];
    {
        float4 a0 = *(const float4*)(attn_v + (size_t)n * 8);
        float4 a1 = *(const float4*)(attn_v + (size_t)n * 8 + 4);
        av[0] = a0.x; av[1] = a0.y; av[2] = a0.z; av[3] = a0.w;
        av[4] = a1.x; av[5] = a1.y; av[6] = a1.z; av[7] = a1.w;
    }
    int hsel = lane & 7;
    float m[8];
    #pragma unroll
    for (int hh = 0; hh < 8; ++hh) m[hh] = -3.0e38f;
    float m_sel = -3.0e38f, den_sel = 0.f, acc0 = 0.f, acc1 = 0.f;

    for (int base = 0; base < deg; base += 64) {
        int nact = min(64, deg - base);
        bool act = (lane < nact);
        int sn = act ? src_sorted[rs + base + lane] : 0;
        float sc[8];
        if (act) {
            float4 a0 = *(const float4*)(attn_u + (size_t)sn * 8);
            float4 a1 = *(const float4*)(attn_u + (size_t)sn * 8 + 4);
            float au[8] = {a0.x, a0.y, a0.z, a0.w, a1.x, a1.y, a1.z, a1.w};
            #pragma unroll
            for (int hh = 0; hh < 8; ++hh) {
                float v = au[hh] + av[hh];
                sc[hh] = (v >= 0.f) ? v : 0.2f * v;
            }
        } else {
            #pragma unroll
            for (int hh = 0; hh < 8; ++hh) sc[hh] = -3.0e38f;
        }
        float cm[8];
        #pragma unroll
        for (int hh = 0; hh < 8; ++hh) cm[hh] = sc[hh];
        #pragma unroll
        for (int d = 1; d < 64; d <<= 1) {
            #pragma unroll
            for (int hh = 0; hh < 8; ++hh)
                cm[hh] = fmaxf(cm[hh], __shfl_xor(cm[hh], d, 64));
        }
        float mn[8], p[8];
        #pragma unroll
        for (int hh = 0; hh < 8; ++hh) {
            mn[hh] = fmaxf(m[hh], cm[hh]);
            p[hh] = expf(sc[hh] - mn[hh]);
        }
        float csum[8];
        #pragma unroll
        for (int hh = 0; hh < 8; ++hh) csum[hh] = p[hh];
        #pragma unroll
        for (int d = 1; d < 64; d <<= 1) {
            #pragma unroll
            for (int hh = 0; hh < 8; ++hh)
                csum[hh] += __shfl_xor(csum[hh], d, 64);
        }
        float mn_sel = select8(mn, hsel);
        float scale_sel = expf(m_sel - mn_sel);
        float csum_sel = select8(csum, hsel);
        den_sel = den_sel * scale_sel + csum_sel;
        m_sel = mn_sel;
        #pragma unroll
        for (int hh = 0; hh < 8; ++hh) m[hh] = mn[hh];

        #pragma unroll
        for (int hh = 0; hh < 8; ++hh) p_lds[w][lane][hh] = p[hh];
        s_lds[w][lane] = sn;
        __threadfence_block();

        acc0 *= scale_sel;
        acc1 *= scale_sel;
        for (int j = 0; j < nact; ++j) {
            int sj = s_lds[w][j];
            float pj = p_lds[w][j][hsel];
            const unsigned short* hr = comb_h1 + (size_t)sj * 256;
            acc0 = fmaf(pj, bf2f(hr[lane]), acc0);
            acc1 = fmaf(pj, bf2f(hr[64 + lane]), acc1);
        }
    }
    float inv = 1.0f / den_sel;
    msg_out[lane] = f2bf(acc0 * inv);
    msg_out[64 + lane] = f2bf(acc1 * inv);
}

// ---------------------------------------------------------------------------
// Fused FF with bf16 MFMA:  out = gelu(comb @ W1 + b1) @ W2 + b2
// block = 256 threads (4 waves), 64 rows/block
// ---------------------------------------------------------------------------
__global__ __launch_bounds__(256, 2) void k_ff(
        const unsigned short* __restrict__ comb,
        const unsigned short* __restrict__ W1T, const float* __restrict__ b1,
        const unsigned short* __restrict__ W2T, const float* __restrict__ b2,
        float* __restrict__ out, int N)
{
    __shared__ unsigned short smem[64 * 520];
    int t = threadIdx.x;
    int lane = t & 63, w = t >> 6;
    int row0 = blockIdx.x * 64;
    const int g = lane >> 4, r16 = lane & 15;

    #pragma unroll
    for (int u = 0; u < 8; ++u) {
        int idx = t + u * 256;
        int r = idx >> 5, c8 = idx & 31;
        bf16x8 v = {0, 0, 0, 0, 0, 0, 0, 0};
        if (row0 + r < N)
            v = *(const bf16x8*)(comb + (size_t)(row0 + r) * 256 + c8 * 8);
        *(bf16x8*)&smem[r * 264 + c8 * 8] = v;
    }
    __syncthreads();

    f32x4 acc[4][8];
    #pragma unroll
    for (int mf = 0; mf < 4; ++mf)
        #pragma unroll
        for (int nf = 0; nf < 8; ++nf)
            acc[mf][nf] = (f32x4){0.f, 0.f, 0.f, 0.f};

    int wcol = w * 128;
    for (int ks = 0; ks < 256; ks += 32) {
        bf16x8 a[4], b[8];
        #pragma unroll
        for (int mf = 0; mf < 4; ++mf)
            a[mf] = *(const bf16x8*)&smem[(mf * 16 + r16) * 264 + ks + g * 8];
        #pragma unroll
        for (int nf = 0; nf < 8; ++nf)
            b[nf] = *(const bf16x8*)(W1T + (size_t)(wcol + nf * 16 + r16) * 256 + ks + g * 8);
        #pragma unroll
        for (int mf = 0; mf < 4; ++mf)
            #pragma unroll
            for (int nf = 0; nf < 8; ++nf)
                acc[mf][nf] = __builtin_amdgcn_mfma_f32_16x16x32_bf16(
                                  a[mf], b[nf], acc[mf][nf], 0, 0, 0);
    }
    __syncthreads();

    #pragma unroll
    for (int nf = 0; nf < 8; ++nf) {
        int col = wcol + nf * 16 + r16;
        float bb = b1[col];
        #pragma unroll
        for (int mf = 0; mf < 4; ++mf) {
            #pragma unroll
            for (int q = 0; q < 4; ++q) {
                int row = mf * 16 + g * 4 + q;
                smem[row * 520 + col] = f2bf(gelu_exact(acc[mf][nf][q] + bb));
            }
        }
    }
    __syncthreads();

    f32x4 acc2[4][2];
    #pragma unroll
    for (int mf = 0; mf < 4; ++mf)
        #pragma unroll
        for (int nf = 0; nf < 2; ++nf)
            acc2[mf][nf] = (f32x4){0.f, 0.f, 0.f, 0.f};

    int ocol = w * 32;
    for (int ks = 0; ks < 512; ks += 32) {
        bf16x8 a[4], b[2];
        #pragma unroll
        for (int mf = 0; mf < 4; ++mf)
            a[mf] = *(const bf16x8*)&smem[(mf * 16 + r16) * 520 + ks + g * 8];
        #pragma unroll
        for (int nf = 0; nf < 2; ++nf)
            b[nf] = *(const bf16x8*)(W2T + (size_t)(ocol + nf * 16 + r16) * 512 + ks + g * 8);
        #pragma unroll
        for (int mf = 0; mf < 4; ++mf)
            #pragma unroll
            for (int nf = 0; nf < 2; ++nf)
                acc2[mf][nf] = __builtin_amdgcn_mfma_f32_16x16x32_bf16(
                                   a[mf], b[nf], acc2[mf][nf], 0, 0, 0);
    }

    #pragma unroll
    for (int nf = 0; nf < 2; ++nf) {
        int col = ocol + nf * 16 + r16;
        float bb = b2[col];
        #pragma unroll
        for (int mf = 0; mf < 4; ++mf) {
            #pragma unroll
            for (int q = 0; q < 4; ++q) {
                int row = row0 + mf * 16 + g * 4 + q;
                if (row < N)
                    out[(size_t)row * 128 + col] = acc2[mf][nf][q] + bb;
            }
        }
    }
}

// ---------------------------------------------------------------------------
extern "C" void kernel_launch(void* const* d_in, const int* in_sizes, int n_in,
                              void* d_out, int out_size, void* d_ws, size_t ws_size,
                              hipStream_t stream)
{
    const float* h    = (const float*)d_in[0];
    const float* W_in = (const float*)d_in[1];
    const float* b_in = (const float*)d_in[2];
    const float* Wu   = (const float*)d_in[3];
    const float* bu   = (const float*)d_in[4];
    const float* Wv   = (const float*)d_in[5];
    const float* W1   = (const float*)d_in[6];
    const float* b1   = (const float*)d_in[7];
    const float* W2   = (const float*)d_in[8];
    const float* b2   = (const float*)d_in[9];
    const int*   src  = (const int*)d_in[10];
    const int*   dst  = (const int*)d_in[11];
    int N = in_sizes[0] / DIMM;
    int E = in_sizes[10];
    float* out = (float*)d_out;

    char* ws = (char*)d_ws;
    size_t off = 0;
    auto alloc = [&](size_t bytes) -> void* {
        void* p = ws + off;
        off = (off + bytes + 255) & ~(size_t)255;
        return p;
    };
    unsigned short* comb = (unsigned short*)alloc((size_t)N * 256 * 2);
    float* attn_u   = (float*)alloc((size_t)N * 8 * 4);
    float* attn_v   = (float*)alloc((size_t)N * 8 * 4);
    int* row_ptr    = (int*)alloc((size_t)(N + 1) * 4);
    int* bucket_cursor = (int*)alloc((size_t)((N + 15) / 16) * 4);
    int* counts     = (int*)alloc((size_t)N * 4);
    int* src_sorted = (int*)alloc((size_t)E * 4);
    unsigned long long* tmp = (unsigned long long*)alloc((size_t)E * 8);
    unsigned short* W1T = (unsigned short*)alloc((size_t)512 * 256 * 2);
    unsigned short* W2T = (unsigned short*)alloc((size_t)128 * 512 * 2);

    int NB = (N + 15) / 16;

    hipMemsetAsync(counts, 0, (size_t)N * 4, stream);
    k_prep<<<512, 256, 0, stream>>>(W1, W2, W1T, W2T);
    k_h1<<<(N + 15) / 16, 256, 0, stream>>>(h, W_in, b_in, Wu, bu, Wv,
                                            comb, attn_u, attn_v, N);
    k_hist<<<(E + 255) / 256, 256, 0, stream>>>(dst, counts, E);
    k_scan<<<1, 1024, 0, stream>>>(counts, row_ptr, bucket_cursor, N, E);
    k_bucket<<<(E + 255) / 256, 256, 0, stream>>>(src, dst, bucket_cursor, tmp, E);
    k_place<<<NB, 256, 0, stream>>>(tmp, row_ptr, src_sorted, N);
    k_agg<<<(N + 3) / 4, 256, 0, stream>>>(comb, attn_u, attn_v, row_ptr,
                                           src_sorted, comb, N);
    k_ff<<<(N + 63) / 64, 256, 0, stream>>>(comb, W1T, b1, W2T, b2, out, N);
}

// Round 4
// 510.434 us; speedup vs baseline: 1.0770x; 1.0770x over previous
//
#include <hip/hip_runtime.h>
#include <math.h>

#define DIMM 128
#define NHEAD 8

typedef __attribute__((ext_vector_type(8))) short bf16x8;
typedef __attribute__((ext_vector_type(4))) float f32x4;

__device__ __forceinline__ unsigned short f2bf(float x) {
    union { float f; unsigned int u; } v; v.f = x;
    unsigned int r = v.u + 0x7FFFu + ((v.u >> 16) & 1u);
    return (unsigned short)(r >> 16);
}
__device__ __forceinline__ float bf2f(unsigned short u) {
    union { unsigned int u; float f; } v; v.u = ((unsigned int)u) << 16;
    return v.f;
}
__device__ __forceinline__ float gelu_exact(float x) {
    return 0.5f * x * (1.0f + erff(x * 0.70710678118654752f));
}

// ---------------------------------------------------------------------------
// Kernel 1: h1 = h @ W_in + b_in  (f32 compute), write comb cols 0..127 (bf16)
// plus attn_u = h1@Wu+bu, attn_v = h1@Wv (f32)
// ---------------------------------------------------------------------------
__global__ __launch_bounds__(256) void k_h1(
        const float* __restrict__ h,
        const float* __restrict__ W_in, const float* __restrict__ b_in,
        const float* __restrict__ Wu, const float* __restrict__ bu,
        const float* __restrict__ Wv,
        unsigned short* __restrict__ comb,   // [N][256] bf16
        float* __restrict__ attn_u, float* __restrict__ attn_v,
        int N)
{
    __shared__ float h_lds[16][128];
    __shared__ float h1_lds[16][130];
    int t = threadIdx.x;
    int row0 = blockIdx.x * 16;

    #pragma unroll
    for (int u = 0; u < 2; ++u) {
        int idx = t + u * 256;
        int r = idx >> 5;
        int c4 = idx & 31;
        float4 v = make_float4(0.f, 0.f, 0.f, 0.f);
        if (row0 + r < N) v = *(const float4*)(h + (size_t)(row0 + r) * DIMM + c4 * 4);
        *(float4*)&h_lds[r][c4 * 4] = v;
    }
    __syncthreads();

    int col = t & 127;
    int rgrp = t >> 7;
    float acc[8];
    float bi = b_in[col];
    #pragma unroll
    for (int i = 0; i < 8; ++i) acc[i] = bi;
    for (int k = 0; k < 128; ++k) {
        float w = W_in[k * DIMM + col];
        #pragma unroll
        for (int i = 0; i < 8; ++i) acc[i] += h_lds[rgrp * 8 + i][k] * w;
    }
    #pragma unroll
    for (int i = 0; i < 8; ++i) {
        int r = rgrp * 8 + i;
        h1_lds[r][col] = acc[i];
        if (row0 + r < N) comb[(size_t)(row0 + r) * 256 + col] = f2bf(acc[i]);
    }
    __syncthreads();

    {
        int r = t >> 4;
        int j = t & 15;
        int head = j & 7;
        bool isv = (j >= 8);
        const float* W = isv ? Wv : Wu;
        float a = isv ? 0.f : bu[head];
        for (int k = 0; k < 128; ++k) a += h1_lds[r][k] * W[k * NHEAD + head];
        if (row0 + r < N) {
            if (isv) attn_v[(size_t)(row0 + r) * NHEAD + head] = a;
            else     attn_u[(size_t)(row0 + r) * NHEAD + head] = a;
        }
    }
}

// ---------------------------------------------------------------------------
// Weight prep: W1 [256][512] f32 -> W1T [512][256] bf16 ; W2 [512][128] f32 ->
// W2T [128][512] bf16 (B^T panels for MFMA B-fragments)
// ---------------------------------------------------------------------------
__global__ __launch_bounds__(256) void k_prep(
        const float* __restrict__ W1, const float* __restrict__ W2,
        unsigned short* __restrict__ W1T, unsigned short* __restrict__ W2T)
{
    int i = blockIdx.x * 256 + threadIdx.x;
    if (i < 256 * 512) {
        int k = i >> 9, j = i & 511;
        W1T[(size_t)j * 256 + k] = f2bf(W1[i]);
    }
    if (i < 512 * 128) {
        int k = i >> 7, j = i & 127;
        W2T[(size_t)j * 512 + k] = f2bf(W2[i]);
    }
}

// ---------------------------------------------------------------------------
// CSR build: histogram -> scan -> XCD-range-partitioned direct scatter
// ---------------------------------------------------------------------------
__global__ void k_hist(const int* __restrict__ dst, int* __restrict__ counts, int E) {
    int e = blockIdx.x * blockDim.x + threadIdx.x;
    if (e < E) atomicAdd(&counts[dst[e]], 1);
}

__global__ __launch_bounds__(1024) void k_scan(
        const int* __restrict__ counts,
        int* __restrict__ row_ptr, int* __restrict__ cursor, int N, int E)
{
    __shared__ int wsum[16];
    int t = threadIdx.x;
    int chunk = (N + 1023) / 1024;
    int s = t * chunk;
    int epos = min(s + chunk, N);
    int local = 0;
    for (int i = s; i < epos; ++i) local += counts[i];

    int lane = t & 63, w = t >> 6;
    int incl = local;
    #pragma unroll
    for (int d = 1; d < 64; d <<= 1) {
        int v = __shfl_up(incl, d, 64);
        if (lane >= d) incl += v;
    }
    if (lane == 63) wsum[w] = incl;
    __syncthreads();
    if (t == 0) {
        int run = 0;
        #pragma unroll
        for (int i = 0; i < 16; ++i) { int v = wsum[i]; wsum[i] = run; run += v; }
    }
    __syncthreads();
    int run = wsum[w] + incl - local;
    for (int i = s; i < epos; ++i) {
        row_ptr[i] = run;
        cursor[i] = run;
        run += counts[i];
    }
    if (t == 1023) row_ptr[N] = E;
}

// Direct scatter, XCD-write-locality version.
// block b: edge slice = b>>3, dst-range = b&7. Only edges whose dst falls in
// this block's range are written; range r is written ONLY by blocks b&7==r
// (one XCD under round-robin dispatch) -> src_sorted lines stay in that XCD's
// L2 until fully written. Edge reads are nontemporal (stream from L3, don't
// evict the hot write lines). Every edge matches exactly one range.
__global__ __launch_bounds__(256) void k_scatter2(
        const int* __restrict__ src, const int* __restrict__ dst,
        int* __restrict__ cursor, unsigned short* __restrict__ src_sorted,
        int E, int nslices, float inv8)
{
    int b = blockIdx.x;
    int range = b & 7;
    int slice = b >> 3;
    int per = (E + nslices - 1) / nslices;
    int s0 = slice * per;
    int s1 = min(s0 + per, E);
    for (int e = s0 + (int)threadIdx.x; e < s1; e += 256) {
        int d = __builtin_nontemporal_load(dst + e);
        int r = min(7, (int)((float)d * inv8));
        if (r == range) {
            int s = __builtin_nontemporal_load(src + e);
            int p = atomicAdd(&cursor[d], 1);
            src_sorted[p] = (unsigned short)s;
        }
    }
}

// ---------------------------------------------------------------------------
// per-dst-node online softmax + message aggregation (f32 math, bf16 h1 gather)
// ---------------------------------------------------------------------------
__device__ __forceinline__ float select8(const float v[8], int h) {
    float a = (h & 1) ? v[1] : v[0];
    float b = (h & 1) ? v[3] : v[2];
    float c = (h & 1) ? v[5] : v[4];
    float d = (h & 1) ? v[7] : v[6];
    float e = (h & 2) ? b : a;
    float f = (h & 2) ? d : c;
    return (h & 4) ? f : e;
}

__global__ __launch_bounds__(256) void k_agg(
        const unsigned short* __restrict__ comb_h1,   // [N][256] bf16, h1 = cols 0..127
        const float* __restrict__ attn_u, const float* __restrict__ attn_v,
        const int* __restrict__ row_ptr, const unsigned short* __restrict__ src_sorted,
        unsigned short* __restrict__ comb,            // msg -> cols 128..255
        int N)
{
    __shared__ float p_lds[4][64][8];
    __shared__ int   s_lds[4][64];
    int t = threadIdx.x;
    int w = t >> 6, lane = t & 63;
    int n = blockIdx.x * 4 + w;
    if (n >= N) return;
    int rs = row_ptr[n], re = row_ptr[n + 1];
    int deg = re - rs;
    unsigned short* msg_out = comb + (size_t)n * 256 + 128;
    if (deg == 0) {
        msg_out[lane] = 0;
        msg_out[64 + lane] = 0;
        return;
    }

    float av[8];
    {
        float4 a0 = *(const float4*)(attn_v + (size_t)n * 8);
        float4 a1 = *(const float4*)(attn_v + (size_t)n * 8 + 4);
        av[0] = a0.x; av[1] = a0.y; av[2] = a0.z; av[3] = a0.w;
        av[4] = a1.x; av[5] = a1.y; av[6] = a1.z; av[7] = a1.w;
    }
    int hsel = lane & 7;
    float m[8];
    #pragma unroll
    for (int hh = 0; hh < 8; ++hh) m[hh] = -3.0e38f;
    float m_sel = -3.0e38f, den_sel = 0.f, acc0 = 0.f, acc1 = 0.f;

    for (int base = 0; base < deg; base += 64) {
        int nact = min(64, deg - base);
        bool act = (lane < nact);
        int sn = act ? (int)src_sorted[rs + base + lane] : 0;
        float sc[8];
        if (act) {
            float4 a0 = *(const float4*)(attn_u + (size_t)sn * 8);
            float4 a1 = *(const float4*)(attn_u + (size_t)sn * 8 + 4);
            float au[8] = {a0.x, a0.y, a0.z, a0.w, a1.x, a1.y, a1.z, a1.w};
            #pragma unroll
            for (int hh = 0; hh < 8; ++hh) {
                float v = au[hh] + av[hh];
                sc[hh] = (v >= 0.f) ? v : 0.2f * v;
            }
        } else {
            #pragma unroll
            for (int hh = 0; hh < 8; ++hh) sc[hh] = -3.0e38f;
        }
        float cm[8];
        #pragma unroll
        for (int hh = 0; hh < 8; ++hh) cm[hh] = sc[hh];
        #pragma unroll
        for (int d = 1; d < 64; d <<= 1) {
            #pragma unroll
            for (int hh = 0; hh < 8; ++hh)
                cm[hh] = fmaxf(cm[hh], __shfl_xor(cm[hh], d, 64));
        }
        float mn[8], p[8];
        #pragma unroll
        for (int hh = 0; hh < 8; ++hh) {
            mn[hh] = fmaxf(m[hh], cm[hh]);
            p[hh] = expf(sc[hh] - mn[hh]);
        }
        float csum[8];
        #pragma unroll
        for (int hh = 0; hh < 8; ++hh) csum[hh] = p[hh];
        #pragma unroll
        for (int d = 1; d < 64; d <<= 1) {
            #pragma unroll
            for (int hh = 0; hh < 8; ++hh)
                csum[hh] += __shfl_xor(csum[hh], d, 64);
        }
        float mn_sel = select8(mn, hsel);
        float scale_sel = expf(m_sel - mn_sel);
        float csum_sel = select8(csum, hsel);
        den_sel = den_sel * scale_sel + csum_sel;
        m_sel = mn_sel;
        #pragma unroll
        for (int hh = 0; hh < 8; ++hh) m[hh] = mn[hh];

        #pragma unroll
        for (int hh = 0; hh < 8; ++hh) p_lds[w][lane][hh] = p[hh];
        s_lds[w][lane] = sn;
        __threadfence_block();

        acc0 *= scale_sel;
        acc1 *= scale_sel;
        for (int j = 0; j < nact; ++j) {
            int sj = s_lds[w][j];
            float pj = p_lds[w][j][hsel];
            const unsigned short* hr = comb_h1 + (size_t)sj * 256;
            acc0 = fmaf(pj, bf2f(hr[lane]), acc0);
            acc1 = fmaf(pj, bf2f(hr[64 + lane]), acc1);
        }
    }
    float inv = 1.0f / den_sel;
    msg_out[lane] = f2bf(acc0 * inv);
    msg_out[64 + lane] = f2bf(acc1 * inv);
}

// ---------------------------------------------------------------------------
// Fused FF with bf16 MFMA:  out = gelu(comb @ W1 + b1) @ W2 + b2
// block = 256 threads (4 waves), 64 rows/block
// ---------------------------------------------------------------------------
__global__ __launch_bounds__(256, 2) void k_ff(
        const unsigned short* __restrict__ comb,
        const unsigned short* __restrict__ W1T, const float* __restrict__ b1,
        const unsigned short* __restrict__ W2T, const float* __restrict__ b2,
        float* __restrict__ out, int N)
{
    __shared__ unsigned short smem[64 * 520];
    int t = threadIdx.x;
    int lane = t & 63, w = t >> 6;
    int row0 = blockIdx.x * 64;
    const int g = lane >> 4, r16 = lane & 15;

    #pragma unroll
    for (int u = 0; u < 8; ++u) {
        int idx = t + u * 256;
        int r = idx >> 5, c8 = idx & 31;
        bf16x8 v = {0, 0, 0, 0, 0, 0, 0, 0};
        if (row0 + r < N)
            v = *(const bf16x8*)(comb + (size_t)(row0 + r) * 256 + c8 * 8);
        *(bf16x8*)&smem[r * 264 + c8 * 8] = v;
    }
    __syncthreads();

    f32x4 acc[4][8];
    #pragma unroll
    for (int mf = 0; mf < 4; ++mf)
        #pragma unroll
        for (int nf = 0; nf < 8; ++nf)
            acc[mf][nf] = (f32x4){0.f, 0.f, 0.f, 0.f};

    int wcol = w * 128;
    for (int ks = 0; ks < 256; ks += 32) {
        bf16x8 a[4], b[8];
        #pragma unroll
        for (int mf = 0; mf < 4; ++mf)
            a[mf] = *(const bf16x8*)&smem[(mf * 16 + r16) * 264 + ks + g * 8];
        #pragma unroll
        for (int nf = 0; nf < 8; ++nf)
            b[nf] = *(const bf16x8*)(W1T + (size_t)(wcol + nf * 16 + r16) * 256 + ks + g * 8);
        #pragma unroll
        for (int mf = 0; mf < 4; ++mf)
            #pragma unroll
            for (int nf = 0; nf < 8; ++nf)
                acc[mf][nf] = __builtin_amdgcn_mfma_f32_16x16x32_bf16(
                                  a[mf], b[nf], acc[mf][nf], 0, 0, 0);
    }
    __syncthreads();

    #pragma unroll
    for (int nf = 0; nf < 8; ++nf) {
        int col = wcol + nf * 16 + r16;
        float bb = b1[col];
        #pragma unroll
        for (int mf = 0; mf < 4; ++mf) {
            #pragma unroll
            for (int q = 0; q < 4; ++q) {
                int row = mf * 16 + g * 4 + q;
                smem[row * 520 + col] = f2bf(gelu_exact(acc[mf][nf][q] + bb));
            }
        }
    }
    __syncthreads();

    f32x4 acc2[4][2];
    #pragma unroll
    for (int mf = 0; mf < 4; ++mf)
        #pragma unroll
        for (int nf = 0; nf < 2; ++nf)
            acc2[mf][nf] = (f32x4){0.f, 0.f, 0.f, 0.f};

    int ocol = w * 32;
    for (int ks = 0; ks < 512; ks += 32) {
        bf16x8 a[4], b[2];
        #pragma unroll
        for (int mf = 0; mf < 4; ++mf)
            a[mf] = *(const bf16x8*)&smem[(mf * 16 + r16) * 520 + ks + g * 8];
        #pragma unroll
        for (int nf = 0; nf < 2; ++nf)
            b[nf] = *(const bf16x8*)(W2T + (size_t)(ocol + nf * 16 + r16) * 512 + ks + g * 8);
        #pragma unroll
        for (int mf = 0; mf < 4; ++mf)
            #pragma unroll
            for (int nf = 0; nf < 2; ++nf)
                acc2[mf][nf] = __builtin_amdgcn_mfma_f32_16x16x32_bf16(
                                   a[mf], b[nf], acc2[mf][nf], 0, 0, 0);
    }

    #pragma unroll
    for (int nf = 0; nf < 2; ++nf) {
        int col = ocol + nf * 16 + r16;
        float bb = b2[col];
        #pragma unroll
        for (int mf = 0; mf < 4; ++mf) {
            #pragma unroll
            for (int q = 0; q < 4; ++q) {
                int row = row0 + mf * 16 + g * 4 + q;
                if (row < N)
                    out[(size_t)row * 128 + col] = acc2[mf][nf][q] + bb;
            }
        }
    }
}

// ---------------------------------------------------------------------------
extern "C" void kernel_launch(void* const* d_in, const int* in_sizes, int n_in,
                              void* d_out, int out_size, void* d_ws, size_t ws_size,
                              hipStream_t stream)
{
    const float* h    = (const float*)d_in[0];
    const float* W_in = (const float*)d_in[1];
    const float* b_in = (const float*)d_in[2];
    const float* Wu   = (const float*)d_in[3];
    const float* bu   = (const float*)d_in[4];
    const float* Wv   = (const float*)d_in[5];
    const float* W1   = (const float*)d_in[6];
    const float* b1   = (const float*)d_in[7];
    const float* W2   = (const float*)d_in[8];
    const float* b2   = (const float*)d_in[9];
    const int*   src  = (const int*)d_in[10];
    const int*   dst  = (const int*)d_in[11];
    int N = in_sizes[0] / DIMM;
    int E = in_sizes[10];
    float* out = (float*)d_out;

    char* ws = (char*)d_ws;
    size_t off = 0;
    auto alloc = [&](size_t bytes) -> void* {
        void* p = ws + off;
        off = (off + bytes + 255) & ~(size_t)255;
        return p;
    };
    unsigned short* comb = (unsigned short*)alloc((size_t)N * 256 * 2);
    float* attn_u   = (float*)alloc((size_t)N * 8 * 4);
    float* attn_v   = (float*)alloc((size_t)N * 8 * 4);
    int* row_ptr    = (int*)alloc((size_t)(N + 1) * 4);
    int* cursor     = (int*)alloc((size_t)N * 4);
    int* counts     = (int*)alloc((size_t)N * 4);
    unsigned short* src_sorted = (unsigned short*)alloc((size_t)E * 2);
    unsigned short* W1T = (unsigned short*)alloc((size_t)512 * 256 * 2);
    unsigned short* W2T = (unsigned short*)alloc((size_t)128 * 512 * 2);

    const int NSLICES = 128;
    float inv8 = 8.0f / (float)N;

    hipMemsetAsync(counts, 0, (size_t)N * 4, stream);
    k_prep<<<512, 256, 0, stream>>>(W1, W2, W1T, W2T);
    k_h1<<<(N + 15) / 16, 256, 0, stream>>>(h, W_in, b_in, Wu, bu, Wv,
                                            comb, attn_u, attn_v, N);
    k_hist<<<(E + 255) / 256, 256, 0, stream>>>(dst, counts, E);
    k_scan<<<1, 1024, 0, stream>>>(counts, row_ptr, cursor, N, E);
    k_scatter2<<<NSLICES * 8, 256, 0, stream>>>(src, dst, cursor, src_sorted,
                                                E, NSLICES, inv8);
    k_agg<<<(N + 3) / 4, 256, 0, stream>>>(comb, attn_u, attn_v, row_ptr,
                                           src_sorted, comb, N);
    k_ff<<<(N + 63) / 64, 256, 0, stream>>>(comb, W1T, b1, W2T, b2, out, N);
}

// Round 5
// 498.752 us; speedup vs baseline: 1.1023x; 1.0234x over previous
//
#include <hip/hip_runtime.h>
#include <math.h>

#define DIMM 128
#define NHEAD 8

typedef __attribute__((ext_vector_type(8))) short bf16x8;
typedef __attribute__((ext_vector_type(4))) float f32x4;

__device__ __forceinline__ unsigned short f2bf(float x) {
    union { float f; unsigned int u; } v; v.f = x;
    unsigned int r = v.u + 0x7FFFu + ((v.u >> 16) & 1u);
    return (unsigned short)(r >> 16);
}
__device__ __forceinline__ float bf2f(unsigned short u) {
    union { unsigned int u; float f; } v; v.u = ((unsigned int)u) << 16;
    return v.f;
}
__device__ __forceinline__ float gelu_exact(float x) {
    return 0.5f * x * (1.0f + erff(x * 0.70710678118654752f));
}

// ---------------------------------------------------------------------------
// Kernel 1: h1 = h @ W_in + b_in (f32). Outputs:
//   h1c [N][128] bf16  (k_ff A-tile, normal layout)
//   hg  [N][128] bf16  (k_agg gather copy, dims (l, l+64) packed per dword)
//   au  [N][8]   bf16  (attn_u), av [N][8] bf16 (attn_v)
// ---------------------------------------------------------------------------
__global__ __launch_bounds__(256) void k_h1(
        const float* __restrict__ h,
        const float* __restrict__ W_in, const float* __restrict__ b_in,
        const float* __restrict__ Wu, const float* __restrict__ bu,
        const float* __restrict__ Wv,
        unsigned short* __restrict__ h1c,
        unsigned int*   __restrict__ hg,     // viewed as dword pairs
        unsigned short* __restrict__ au, unsigned short* __restrict__ av,
        int N)
{
    __shared__ float h_lds[16][128];
    __shared__ float h1_lds[16][130];
    int t = threadIdx.x;
    int row0 = blockIdx.x * 16;

    #pragma unroll
    for (int u = 0; u < 2; ++u) {
        int idx = t + u * 256;
        int r = idx >> 5;
        int c4 = idx & 31;
        float4 v = make_float4(0.f, 0.f, 0.f, 0.f);
        if (row0 + r < N) v = *(const float4*)(h + (size_t)(row0 + r) * DIMM + c4 * 4);
        *(float4*)&h_lds[r][c4 * 4] = v;
    }
    __syncthreads();

    int col = t & 127;
    int rgrp = t >> 7;
    float acc[8];
    float bi = b_in[col];
    #pragma unroll
    for (int i = 0; i < 8; ++i) acc[i] = bi;
    for (int k = 0; k < 128; ++k) {
        float w = W_in[k * DIMM + col];
        #pragma unroll
        for (int i = 0; i < 8; ++i) acc[i] += h_lds[rgrp * 8 + i][k] * w;
    }
    #pragma unroll
    for (int i = 0; i < 8; ++i) {
        int r = rgrp * 8 + i;
        h1_lds[r][col] = acc[i];
        if (row0 + r < N) h1c[(size_t)(row0 + r) * 128 + col] = f2bf(acc[i]);
    }
    __syncthreads();

    // attn projections (bf16 out)
    {
        int r = t >> 4;
        int j = t & 15;
        int head = j & 7;
        bool isv = (j >= 8);
        const float* W = isv ? Wv : Wu;
        float a = isv ? 0.f : bu[head];
        for (int k = 0; k < 128; ++k) a += h1_lds[r][k] * W[k * NHEAD + head];
        if (row0 + r < N) {
            if (isv) av[(size_t)(row0 + r) * 8 + head] = f2bf(a);
            else     au[(size_t)(row0 + r) * 8 + head] = f2bf(a);
        }
    }

    // hg pack: dword l of row = (bf16(h1[l+64]) << 16) | bf16(h1[l])
    {
        int l = t & 63;
        int rg4 = t >> 6;   // 4 groups x 4 rows
        #pragma unroll
        for (int rr = 0; rr < 4; ++rr) {
            int r = rg4 * 4 + rr;
            if (row0 + r < N) {
                unsigned int lo = f2bf(h1_lds[r][l]);
                unsigned int hi = f2bf(h1_lds[r][l + 64]);
                hg[(size_t)(row0 + r) * 64 + l] = (hi << 16) | lo;
            }
        }
    }
}

// ---------------------------------------------------------------------------
// Weight prep: W1 -> W1T bf16, W2 -> W2T bf16 (B^T panels)
// ---------------------------------------------------------------------------
__global__ __launch_bounds__(256) void k_prep(
        const float* __restrict__ W1, const float* __restrict__ W2,
        unsigned short* __restrict__ W1T, unsigned short* __restrict__ W2T)
{
    int i = blockIdx.x * 256 + threadIdx.x;
    if (i < 256 * 512) {
        int k = i >> 9, j = i & 511;
        W1T[(size_t)j * 256 + k] = f2bf(W1[i]);
    }
    if (i < 512 * 128) {
        int k = i >> 7, j = i & 127;
        W2T[(size_t)j * 512 + k] = f2bf(W2[i]);
    }
}

// ---------------------------------------------------------------------------
// CSR build: histogram -> scan -> XCD-range-partitioned direct scatter
// ---------------------------------------------------------------------------
__global__ void k_hist(const int* __restrict__ dst, int* __restrict__ counts, int E) {
    int e = blockIdx.x * blockDim.x + threadIdx.x;
    if (e < E) atomicAdd(&counts[dst[e]], 1);
}

__global__ __launch_bounds__(1024) void k_scan(
        const int* __restrict__ counts,
        int* __restrict__ row_ptr, int* __restrict__ cursor, int N, int E)
{
    __shared__ int wsum[16];
    int t = threadIdx.x;
    int chunk = (N + 1023) / 1024;
    int s = t * chunk;
    int epos = min(s + chunk, N);
    int local = 0;
    for (int i = s; i < epos; ++i) local += counts[i];

    int lane = t & 63, w = t >> 6;
    int incl = local;
    #pragma unroll
    for (int d = 1; d < 64; d <<= 1) {
        int v = __shfl_up(incl, d, 64);
        if (lane >= d) incl += v;
    }
    if (lane == 63) wsum[w] = incl;
    __syncthreads();
    if (t == 0) {
        int run = 0;
        #pragma unroll
        for (int i = 0; i < 16; ++i) { int v = wsum[i]; wsum[i] = run; run += v; }
    }
    __syncthreads();
    int run = wsum[w] + incl - local;
    for (int i = s; i < epos; ++i) {
        row_ptr[i] = run;
        cursor[i] = run;
        run += counts[i];
    }
    if (t == 1023) row_ptr[N] = E;
}

// Direct scatter, XCD-write-locality: block b handles edge slice b>>3, and
// writes only dst-range b&7 (one XCD under round-robin dispatch).
__global__ __launch_bounds__(256) void k_scatter2(
        const int* __restrict__ src, const int* __restrict__ dst,
        int* __restrict__ cursor, unsigned short* __restrict__ src_sorted,
        int E, int nslices, float inv8)
{
    int b = blockIdx.x;
    int range = b & 7;
    int slice = b >> 3;
    int per = (E + nslices - 1) / nslices;
    int s0 = slice * per;
    int s1 = min(s0 + per, E);
    for (int e = s0 + (int)threadIdx.x; e < s1; e += 256) {
        int d = __builtin_nontemporal_load(dst + e);
        int r = min(7, (int)((float)d * inv8));
        if (r == range) {
            int s = __builtin_nontemporal_load(src + e);
            int p = atomicAdd(&cursor[d], 1);
            src_sorted[p] = (unsigned short)s;
        }
    }
}

// ---------------------------------------------------------------------------
// per-dst-node online softmax + message aggregation
// one wave per node; lane l owns dims {l, l+64} (head l&7); gather = 1 dword
// ---------------------------------------------------------------------------
__device__ __forceinline__ float select8(const float v[8], int h) {
    float a = (h & 1) ? v[1] : v[0];
    float b = (h & 1) ? v[3] : v[2];
    float c = (h & 1) ? v[5] : v[4];
    float d = (h & 1) ? v[7] : v[6];
    float e = (h & 2) ? b : a;
    float f = (h & 2) ? d : c;
    return (h & 4) ? f : e;
}

__global__ __launch_bounds__(256) void k_agg(
        const unsigned int* __restrict__ hg,      // [N][64] dword pairs
        const unsigned short* __restrict__ au,    // [N][8] bf16
        const unsigned short* __restrict__ av,    // [N][8] bf16
        const int* __restrict__ row_ptr, const unsigned short* __restrict__ src_sorted,
        unsigned short* __restrict__ msgc,        // [N][128] bf16
        int N)
{
    __shared__ float p_lds[4][8][68];   // stride 68: read banks 4h+j, conflict-free
    __shared__ int   s_lds[4][64];
    int t = threadIdx.x;
    int w = t >> 6, lane = t & 63;
    int n = blockIdx.x * 4 + w;
    if (n >= N) return;
    int rs = row_ptr[n], re = row_ptr[n + 1];
    int deg = re - rs;
    unsigned short* msg_out = msgc + (size_t)n * 128;
    if (deg == 0) {
        msg_out[lane] = 0;
        msg_out[64 + lane] = 0;
        return;
    }

    float avf[8];
    {
        bf16x8 a8 = *(const bf16x8*)(av + (size_t)n * 8);
        #pragma unroll
        for (int hh = 0; hh < 8; ++hh) avf[hh] = bf2f((unsigned short)a8[hh]);
    }
    int hsel = lane & 7;
    float m[8];
    #pragma unroll
    for (int hh = 0; hh < 8; ++hh) m[hh] = -3.0e38f;
    float m_sel = -3.0e38f, den_sel = 0.f, accA = 0.f, accB = 0.f;

    for (int base = 0; base < deg; base += 64) {
        int nact = min(64, deg - base);
        bool act = (lane < nact);
        int sn = act ? (int)src_sorted[rs + base + lane] : 0;
        float sc[8];
        if (act) {
            bf16x8 u8 = *(const bf16x8*)(au + (size_t)sn * 8);
            #pragma unroll
            for (int hh = 0; hh < 8; ++hh) {
                float v = bf2f((unsigned short)u8[hh]) + avf[hh];
                sc[hh] = (v >= 0.f) ? v : 0.2f * v;
            }
        } else {
            #pragma unroll
            for (int hh = 0; hh < 8; ++hh) sc[hh] = -3.0e38f;
        }
        // per-head chunk max
        float cm[8];
        #pragma unroll
        for (int hh = 0; hh < 8; ++hh) cm[hh] = sc[hh];
        #pragma unroll
        for (int d = 1; d < 64; d <<= 1) {
            #pragma unroll
            for (int hh = 0; hh < 8; ++hh)
                cm[hh] = fmaxf(cm[hh], __shfl_xor(cm[hh], d, 64));
        }
        float mn[8], p[8];
        #pragma unroll
        for (int hh = 0; hh < 8; ++hh) {
            mn[hh] = fmaxf(m[hh], cm[hh]);
            p[hh] = expf(sc[hh] - mn[hh]);
        }
        float csum[8];
        #pragma unroll
        for (int hh = 0; hh < 8; ++hh) csum[hh] = p[hh];
        #pragma unroll
        for (int d = 1; d < 64; d <<= 1) {
            #pragma unroll
            for (int hh = 0; hh < 8; ++hh)
                csum[hh] += __shfl_xor(csum[hh], d, 64);
        }
        float mn_sel = select8(mn, hsel);
        float scale_sel = expf(m_sel - mn_sel);
        float csum_sel = select8(csum, hsel);
        den_sel = den_sel * scale_sel + csum_sel;
        m_sel = mn_sel;
        #pragma unroll
        for (int hh = 0; hh < 8; ++hh) m[hh] = mn[hh];

        #pragma unroll
        for (int hh = 0; hh < 8; ++hh) p_lds[w][hh][lane] = p[hh];
        s_lds[w][lane] = sn;
        __threadfence_block();

        accA *= scale_sel;
        accB *= scale_sel;
        for (int j = 0; j < nact; ++j) {
            int sj = s_lds[w][j];
            float pj = p_lds[w][hsel][j];
            unsigned int g = hg[(size_t)sj * 64 + lane];   // dims (lane, lane+64)
            accA = fmaf(pj, bf2f((unsigned short)(g & 0xffffu)), accA);
            accB = fmaf(pj, bf2f((unsigned short)(g >> 16)), accB);
        }
    }
    float inv = 1.0f / den_sel;
    msg_out[lane] = f2bf(accA * inv);
    msg_out[64 + lane] = f2bf(accB * inv);
}

// ---------------------------------------------------------------------------
// Fused FF with bf16 MFMA:  out = gelu([h1c|msgc] @ W1 + b1) @ W2 + b2
// block = 256 threads (4 waves), 64 rows/block
// ---------------------------------------------------------------------------
__global__ __launch_bounds__(256, 2) void k_ff(
        const unsigned short* __restrict__ h1c,
        const unsigned short* __restrict__ msgc,
        const unsigned short* __restrict__ W1T, const float* __restrict__ b1,
        const unsigned short* __restrict__ W2T, const float* __restrict__ b2,
        float* __restrict__ out, int N)
{
    __shared__ unsigned short smem[64 * 520];
    int t = threadIdx.x;
    int lane = t & 63, w = t >> 6;
    int row0 = blockIdx.x * 64;
    const int g = lane >> 4, r16 = lane & 15;

    #pragma unroll
    for (int u = 0; u < 8; ++u) {
        int idx = t + u * 256;
        int r = idx >> 5, c8 = idx & 31;
        bf16x8 v = {0, 0, 0, 0, 0, 0, 0, 0};
        if (row0 + r < N) {
            const unsigned short* sp = (c8 < 16)
                ? (h1c  + (size_t)(row0 + r) * 128 + c8 * 8)
                : (msgc + (size_t)(row0 + r) * 128 + (c8 - 16) * 8);
            v = *(const bf16x8*)sp;
        }
        *(bf16x8*)&smem[r * 264 + c8 * 8] = v;
    }
    __syncthreads();

    f32x4 acc[4][8];
    #pragma unroll
    for (int mf = 0; mf < 4; ++mf)
        #pragma unroll
        for (int nf = 0; nf < 8; ++nf)
            acc[mf][nf] = (f32x4){0.f, 0.f, 0.f, 0.f};

    int wcol = w * 128;
    for (int ks = 0; ks < 256; ks += 32) {
        bf16x8 a[4], b[8];
        #pragma unroll
        for (int mf = 0; mf < 4; ++mf)
            a[mf] = *(const bf16x8*)&smem[(mf * 16 + r16) * 264 + ks + g * 8];
        #pragma unroll
        for (int nf = 0; nf < 8; ++nf)
            b[nf] = *(const bf16x8*)(W1T + (size_t)(wcol + nf * 16 + r16) * 256 + ks + g * 8);
        #pragma unroll
        for (int mf = 0; mf < 4; ++mf)
            #pragma unroll
            for (int nf = 0; nf < 8; ++nf)
                acc[mf][nf] = __builtin_amdgcn_mfma_f32_16x16x32_bf16(
                                  a[mf], b[nf], acc[mf][nf], 0, 0, 0);
    }
    __syncthreads();

    #pragma unroll
    for (int nf = 0; nf < 8; ++nf) {
        int col = wcol + nf * 16 + r16;
        float bb = b1[col];
        #pragma unroll
        for (int mf = 0; mf < 4; ++mf) {
            #pragma unroll
            for (int q = 0; q < 4; ++q) {
                int row = mf * 16 + g * 4 + q;
                smem[row * 520 + col] = f2bf(gelu_exact(acc[mf][nf][q] + bb));
            }
        }
    }
    __syncthreads();

    f32x4 acc2[4][2];
    #pragma unroll
    for (int mf = 0; mf < 4; ++mf)
        #pragma unroll
        for (int nf = 0; nf < 2; ++nf)
            acc2[mf][nf] = (f32x4){0.f, 0.f, 0.f, 0.f};

    int ocol = w * 32;
    for (int ks = 0; ks < 512; ks += 32) {
        bf16x8 a[4], b[2];
        #pragma unroll
        for (int mf = 0; mf < 4; ++mf)
            a[mf] = *(const bf16x8*)&smem[(mf * 16 + r16) * 520 + ks + g * 8];
        #pragma unroll
        for (int nf = 0; nf < 2; ++nf)
            b[nf] = *(const bf16x8*)(W2T + (size_t)(ocol + nf * 16 + r16) * 512 + ks + g * 8);
        #pragma unroll
        for (int mf = 0; mf < 4; ++mf)
            #pragma unroll
            for (int nf = 0; nf < 2; ++nf)
                acc2[mf][nf] = __builtin_amdgcn_mfma_f32_16x16x32_bf16(
                                   a[mf], b[nf], acc2[mf][nf], 0, 0, 0);
    }

    #pragma unroll
    for (int nf = 0; nf < 2; ++nf) {
        int col = ocol + nf * 16 + r16;
        float bb = b2[col];
        #pragma unroll
        for (int mf = 0; mf < 4; ++mf) {
            #pragma unroll
            for (int q = 0; q < 4; ++q) {
                int row = row0 + mf * 16 + g * 4 + q;
                if (row < N)
                    out[(size_t)row * 128 + col] = acc2[mf][nf][q] + bb;
            }
        }
    }
}

// ---------------------------------------------------------------------------
extern "C" void kernel_launch(void* const* d_in, const int* in_sizes, int n_in,
                              void* d_out, int out_size, void* d_ws, size_t ws_size,
                              hipStream_t stream)
{
    const float* h    = (const float*)d_in[0];
    const float* W_in = (const float*)d_in[1];
    const float* b_in = (const float*)d_in[2];
    const float* Wu   = (const float*)d_in[3];
    const float* bu   = (const float*)d_in[4];
    const float* Wv   = (const float*)d_in[5];
    const float* W1   = (const float*)d_in[6];
    const float* b1   = (const float*)d_in[7];
    const float* W2   = (const float*)d_in[8];
    const float* b2   = (const float*)d_in[9];
    const int*   src  = (const int*)d_in[10];
    const int*   dst  = (const int*)d_in[11];
    int N = in_sizes[0] / DIMM;
    int E = in_sizes[10];
    float* out = (float*)d_out;

    char* ws = (char*)d_ws;
    size_t off = 0;
    auto alloc = [&](size_t bytes) -> void* {
        void* p = ws + off;
        off = (off + bytes + 255) & ~(size_t)255;
        return p;
    };
    unsigned short* h1c  = (unsigned short*)alloc((size_t)N * 128 * 2);
    unsigned int*   hg   = (unsigned int*)alloc((size_t)N * 64 * 4);
    unsigned short* msgc = (unsigned short*)alloc((size_t)N * 128 * 2);
    unsigned short* au   = (unsigned short*)alloc((size_t)N * 8 * 2);
    unsigned short* av   = (unsigned short*)alloc((size_t)N * 8 * 2);
    int* row_ptr    = (int*)alloc((size_t)(N + 1) * 4);
    int* cursor     = (int*)alloc((size_t)N * 4);
    int* counts     = (int*)alloc((size_t)N * 4);
    unsigned short* src_sorted = (unsigned short*)alloc((size_t)E * 2);
    unsigned short* W1T = (unsigned short*)alloc((size_t)512 * 256 * 2);
    unsigned short* W2T = (unsigned short*)alloc((size_t)128 * 512 * 2);

    const int NSLICES = 128;
    float inv8 = 8.0f / (float)N;

    hipMemsetAsync(counts, 0, (size_t)N * 4, stream);
    k_prep<<<512, 256, 0, stream>>>(W1, W2, W1T, W2T);
    k_h1<<<(N + 15) / 16, 256, 0, stream>>>(h, W_in, b_in, Wu, bu, Wv,
                                            h1c, hg, au, av, N);
    k_hist<<<(E + 255) / 256, 256, 0, stream>>>(dst, counts, E);
    k_scan<<<1, 1024, 0, stream>>>(counts, row_ptr, cursor, N, E);
    k_scatter2<<<NSLICES * 8, 256, 0, stream>>>(src, dst, cursor, src_sorted,
                                                E, NSLICES, inv8);
    k_agg<<<(N + 3) / 4, 256, 0, stream>>>(hg, au, av, row_ptr,
                                           src_sorted, msgc, N);
    k_ff<<<(N + 63) / 64, 256, 0, stream>>>(h1c, msgc, W1T, b1, W2T, b2, out, N);
}